// Round 12
// baseline (38.553 us; speedup 1.0000x reference)
//
#include <hip/hip_runtime.h>

// YOLO layer: input [B=16, A*C=255, G=76, G=76] f32, anchors [3,2] f32.
// Output [B, A*G*G=17328, C=85] f32.
//   c=0: (sigmoid+gx)*8, c=1: (sigmoid+gy)*8, c=2: exp*aw, c=3: exp*ah,
//   c>=4: sigmoid   (anchor/stride folded: (e^w * aw/8)*8 == e^w*aw)
//
// R11: burst-length ladder continues. Measured: 64B chunk=37.7us,
// 256B=35.9, 512B=33.8. This round: 1024B contiguous per channel per
// wave-instruction WITHOUT the LDS cost of TILE=256:
//   block = PAIR of 128-tiles (256 consecutive positions). u = t+512i ->
//   wave w, iter i covers channel c=w+8i, all 64 quads = 1024B contiguous.
//   LDS stays [128][85] = 43.5KB (tile A then tile B staged sequentially)
//   -> 3 blocks/CU, 24 waves/CU.
// Non-persistent 1104 blocks (1 pair each): persistent striding would give
// 2:1 pair imbalance; hardware backfill + 3-resident-block TLP replaces the
// R10 prefetch (new blocks' prologue loads overlap old blocks' stores).
// Lessons kept: __syncthreads (R4), plain stores (R5), HIP float4 (R6),
// v_exp/v_rcp (R7), big read bursts (R10).

#define GDIM 76
#define GG 5776            // 76*76
#define NA 3
#define NCH 85
#define PAIR 256           // positions per block (two 128-tiles)
#define HALF 128
#define THREADS 512        // 8 waves
#define PPB 23             // pairs per (b,a): 22*256=5632, last pair 144 pos
#define NBLK (PPB * NA * 16)   // 1104 blocks
#define UNITS (NCH * (PAIR / 4))  // 5440 float4 units per pair
#define LITERS 11                 // ceil(5440/512)
#define SITERS 6                  // ceil(2720/512) store iters per half

__device__ __forceinline__ float fast_sigmoid(float x) {
    // 1/(1+exp(-x)): v_exp_f32 + v_add + v_rcp_f32. ~2 ulp; threshold ~496.
    return __builtin_amdgcn_rcpf(1.0f + __expf(-x));
}

__global__ __launch_bounds__(THREADS) void yolo_kernel(
    const float* __restrict__ in, const float* __restrict__ anchors,
    float* __restrict__ out)
{
    __shared__ float lds[HALF * NCH];   // 43520 B -> 3 blocks/CU

    const int t  = threadIdx.x;
    const int bp = blockIdx.x;
    const int ba = bp / PPB;            // b*3 + a
    const int p  = bp - ba * PPB;
    const int a  = ba % NA;
    const int s0 = p * PAIR;

    const float aw = anchors[2 * a];
    const float ah = anchors[2 * a + 1];
    const float* inb = in + (long)ba * (NCH * GG);

    float4 v[LITERS];

    // ---- load whole pair: wave w iter i = channel w+8i, 1024B contiguous
    #pragma unroll
    for (int i = 0; i < LITERS; ++i) {
        int u = t + i * THREADS;
        if (u < UNITS) {
            int c = u >> 6, q = u & 63;
            int pos = s0 + q * 4;
            if (pos < GG)
                v[i] = *reinterpret_cast<const float4*>(&inb[(long)c * GG + pos]);
        }
    }

    // transform one half (h=0: quads 0..31, h=1: quads 32..63) into LDS
    auto transform_half = [&](int h) {
        #pragma unroll
        for (int i = 0; i < LITERS; ++i) {
            int u = t + i * THREADS;
            if (u < UNITS) {
                int c = u >> 6, q = u & 63;
                if ((q >> 5) == h) {
                    int pos = s0 + q * 4;
                    if (pos < GG) {
                        int qr = q & 31;            // quad within half
                        float r[4] = {v[i].x, v[i].y, v[i].z, v[i].w};
                        if (c == 0) {
                            #pragma unroll
                            for (int k = 0; k < 4; ++k) {
                                int pp = pos + k;
                                float gx = (float)(pp - (pp / GDIM) * GDIM);
                                r[k] = (fast_sigmoid(r[k]) + gx) * 8.0f;
                            }
                        } else if (c == 1) {
                            #pragma unroll
                            for (int k = 0; k < 4; ++k) {
                                int pp = pos + k;
                                float gy = (float)(pp / GDIM);
                                r[k] = (fast_sigmoid(r[k]) + gy) * 8.0f;
                            }
                        } else if (c == 2) {
                            #pragma unroll
                            for (int k = 0; k < 4; ++k) r[k] = __expf(r[k]) * aw;
                        } else if (c == 3) {
                            #pragma unroll
                            for (int k = 0; k < 4; ++k) r[k] = __expf(r[k]) * ah;
                        } else {
                            #pragma unroll
                            for (int k = 0; k < 4; ++k) r[k] = fast_sigmoid(r[k]);
                        }
                        #pragma unroll
                        for (int k = 0; k < 4; ++k)
                            lds[(qr * 4 + k) * NCH + c] = r[k];
                    }
                }
            }
        }
    };

    auto store_half = [&](int h) {
        int hs0   = s0 + h * HALF;
        int valid = (GG - hs0 < HALF) ? (GG - hs0) : HALF;  // 128 or 16
        int n4    = valid * NCH / 4;                         // 2720 or 340
        float4* __restrict__ outv =
            reinterpret_cast<float4*>(out + ((long)ba * GG + hs0) * NCH);
        const float4* ldsv = reinterpret_cast<const float4*>(lds);
        #pragma unroll
        for (int i = 0; i < SITERS; ++i) {
            int f4 = t + i * THREADS;
            if (f4 < n4)
                outv[f4] = ldsv[f4];   // ds_read_b128 + global_store_dwordx4
        }
    };

    transform_half(0);
    __syncthreads();
    store_half(0);
    __syncthreads();          // LDS drained before tile B overwrites
    transform_half(1);
    __syncthreads();
    store_half(1);
}

extern "C" void kernel_launch(void* const* d_in, const int* in_sizes, int n_in,
                              void* d_out, int out_size, void* d_ws, size_t ws_size,
                              hipStream_t stream) {
    const float* pred    = (const float*)d_in[0];
    const float* anchors = (const float*)d_in[1];
    float* out           = (float*)d_out;

    yolo_kernel<<<dim3(NBLK), dim3(THREADS), 0, stream>>>(pred, anchors, out);
}

// Round 13
// 35.196 us; speedup vs baseline: 1.0954x; 1.0954x over previous
//
#include <hip/hip_runtime.h>

// YOLO layer: input [B=16, A*C=255, G=76, G=76] f32, anchors [3,2] f32.
// Output [B, A*G*G=17328, C=85] f32.
//   c=0: (sigmoid+gx)*8, c=1: (sigmoid+gy)*8, c=2: exp*aw, c=3: exp*ah,
//   c>=4: sigmoid   (anchor/stride folded: (e^w * aw/8)*8 == e^w*aw)
//
// R12 = R10 (best, 33.8us: persistent blocks, TILE=128, single-buffer
// prefetch, __syncthreads, 512B read bursts) + LDS XOR-swizzle.
//   R10's ds_write (4q+k)*85+c is a 4-way bank conflict (2.2M cycles:
//   lanes q,q+8,q+16,q+24 collide since 340*8 == 0 mod 128). Write and
//   read use the SAME linear index space, so a 16B-granular permutation
//   applied to both sides is correctness-neutral:
//     swz4(x) = x ^ ((x>>3)&3)    (addr4 steps 680 per Dq=8; (x>>3)&3
//   steps by 85 mod 4 = 1 -> the 4 partners get distinct banks). Store's
//   contiguous b128 reads are permuted within 8-lane groups: still free.
// R11 lesson: don't bundle burst changes with schedule changes (pair-block
// upfront load serialized on the vmcnt FIFO; reverted).

#define GDIM 76
#define GG 5776            // 76*76 (divisible by 4)
#define NA 3
#define NCH 85
#define TILE 128           // spatial positions per block-tile
#define THREADS 512        // 8 waves
#define LOAD_UNITS (NCH * (TILE / 4))  // 2720 float4 units per tile
#define LITERS 6                       // ceil(2720/512)
#define TPB 46                         // tiles per (b,a): ceil(5776/128)
#define NT (TPB * NA * 16)             // 2208 total tiles
#define GRID 768                       // 3 blocks/CU * 256 CUs (LDS cap)

__device__ __forceinline__ float fast_sigmoid(float x) {
    // 1/(1+exp(-x)): v_exp_f32 + v_add + v_rcp_f32. ~2 ulp; threshold ~496.
    return __builtin_amdgcn_rcpf(1.0f + __expf(-x));
}

__global__ __launch_bounds__(THREADS) void yolo_kernel(
    const float* __restrict__ in, const float* __restrict__ anchors,
    float* __restrict__ out)
{
    __shared__ float lds[TILE * NCH];   // 43520 B -> 3 blocks/CU

    const int t = threadIdx.x;

    float4 v[LITERS];

    auto load_tile = [&](int g) {
        int ba   = g / TPB;
        int tile = g - ba * TPB;
        int s0   = tile * TILE;
        const float* inb = in + (long)ba * (NCH * GG);
        #pragma unroll
        for (int i = 0; i < LITERS; ++i) {
            int idx = t + i * THREADS;
            int c   = idx >> 5;         // channel (32 quads per channel)
            int q   = idx & 31;
            int pos = s0 + q * 4;
            if (idx < LOAD_UNITS && pos < GG)
                v[i] = *reinterpret_cast<const float4*>(&inb[(long)c * GG + pos]);
        }
    };

    auto transform_write = [&](int g) {
        int ba   = g / TPB;
        int tile = g - ba * TPB;
        int a    = ba % NA;
        int s0   = tile * TILE;
        float aw = anchors[2 * a];
        float ah = anchors[2 * a + 1];
        #pragma unroll
        for (int i = 0; i < LITERS; ++i) {
            int idx = t + i * THREADS;
            int c   = idx >> 5;
            int q   = idx & 31;
            int pos = s0 + q * 4;
            if (idx < LOAD_UNITS && pos < GG) {
                float r[4] = {v[i].x, v[i].y, v[i].z, v[i].w};
                if (c == 0) {
                    #pragma unroll
                    for (int k = 0; k < 4; ++k) {
                        int p = pos + k;
                        float gx = (float)(p - (p / GDIM) * GDIM);
                        r[k] = (fast_sigmoid(r[k]) + gx) * 8.0f;
                    }
                } else if (c == 1) {
                    #pragma unroll
                    for (int k = 0; k < 4; ++k) {
                        int p = pos + k;
                        float gy = (float)(p / GDIM);
                        r[k] = (fast_sigmoid(r[k]) + gy) * 8.0f;
                    }
                } else if (c == 2) {
                    #pragma unroll
                    for (int k = 0; k < 4; ++k) r[k] = __expf(r[k]) * aw;
                } else if (c == 3) {
                    #pragma unroll
                    for (int k = 0; k < 4; ++k) r[k] = __expf(r[k]) * ah;
                } else {
                    #pragma unroll
                    for (int k = 0; k < 4; ++k) r[k] = fast_sigmoid(r[k]);
                }
                #pragma unroll
                for (int k = 0; k < 4; ++k) {
                    int A  = (q * 4 + k) * NCH + c;          // linear float idx
                    int i4 = A >> 2;
                    int sw = ((i4 ^ ((i4 >> 3) & 3)) << 2) | (A & 3);
                    lds[sw] = r[k];     // swizzled: 4-way conflict -> 2-way
                }
            }
        }
    };

    auto store_tile = [&](int g) {
        int ba    = g / TPB;
        int tile  = g - ba * TPB;
        int s0    = tile * TILE;
        int valid = (GG - s0 < TILE) ? (GG - s0) : TILE;  // 128 or 16
        int n4    = valid * NCH / 4;                       // 2720 or 340
        float4* __restrict__ outv =
            reinterpret_cast<float4*>(out + ((long)ba * GG + s0) * NCH);
        const float4* ldsv = reinterpret_cast<const float4*>(lds);
        #pragma unroll
        for (int i = 0; i < LITERS; ++i) {
            int f4 = t + i * THREADS;
            if (f4 < n4)
                outv[f4] = ldsv[f4 ^ ((f4 >> 3) & 3)];  // same swizzle on read
        }
    };

    int g = blockIdx.x;
    load_tile(g);                       // prologue (every block has >=2 tiles)
    for (; g < NT; g += GRID) {
        transform_write(g);             // consumes v (vmcnt wait), fills LDS
        __syncthreads();
        int gn = g + GRID;
        if (gn < NT) load_tile(gn);     // issue next-tile loads
        store_tile(g);                  // LDS -> global
        __syncthreads();                // LDS drained before next overwrite
    }
}

extern "C" void kernel_launch(void* const* d_in, const int* in_sizes, int n_in,
                              void* d_out, int out_size, void* d_ws, size_t ws_size,
                              hipStream_t stream) {
    const float* pred    = (const float*)d_in[0];
    const float* anchors = (const float*)d_in[1];
    float* out           = (float*)d_out;

    yolo_kernel<<<dim3(GRID), dim3(THREADS), 0, stream>>>(pred, anchors, out);
}

// Round 14
// 33.738 us; speedup vs baseline: 1.1427x; 1.0432x over previous
//
#include <hip/hip_runtime.h>

// YOLO layer: input [B=16, A*C=255, G=76, G=76] f32, anchors [3,2] f32.
// Output [B, A*G*G=17328, C=85] f32.
//   c=0: (sigmoid+gx)*8, c=1: (sigmoid+gy)*8, c=2: exp*aw, c=3: exp*ah,
//   c>=4: sigmoid   (anchor/stride folded: (e^w * aw/8)*8 == e^w*aw)
//
// FINAL = R10 exactly (best, 33.8us): persistent blocks, TILE=128 (512B
// read bursts), single-buffer register prefetch, __syncthreads, HIP float4,
// v_exp/v_rcp transcendentals.
// Ladder: naive 43.2 -> float4 LDS transpose 38.1 -> persistent+prefetch
// 37.2 -> fast transcendentals 35.9 -> TILE=128 33.8us.
// Dead ends (measured): lgkmcnt-only barriers (49.5), nt stores (77),
// 2-deep pipeline (38.0), zero-barrier wave-autonomous (37.7), 1024B
// pair-blocks (38.6), LDS XOR-swizzle (35.2, conflicts unchanged ->
// counter is ds_read_b128 BW-inherent serialization, not waste).
// 186 MB app traffic / 33.8us = 5.5 TB/s = 87% of the 6.29 TB/s copy
// ceiling on an 85-stream strided read + transpose + LDS round-trip.

#define GDIM 76
#define GG 5776            // 76*76 (divisible by 4)
#define NA 3
#define NCH 85
#define TILE 128           // spatial positions per block-tile
#define THREADS 512        // 8 waves
#define LOAD_UNITS (NCH * (TILE / 4))  // 2720 float4 units per tile
#define LITERS 6                       // ceil(2720/512)
#define TPB 46                         // tiles per (b,a): ceil(5776/128)
#define NT (TPB * NA * 16)             // 2208 total tiles
#define GRID 768                       // 3 blocks/CU * 256 CUs (LDS cap)

__device__ __forceinline__ float fast_sigmoid(float x) {
    // 1/(1+exp(-x)): v_exp_f32 + v_add + v_rcp_f32. ~2 ulp; threshold ~496.
    return __builtin_amdgcn_rcpf(1.0f + __expf(-x));
}

__global__ __launch_bounds__(THREADS) void yolo_kernel(
    const float* __restrict__ in, const float* __restrict__ anchors,
    float* __restrict__ out)
{
    __shared__ float lds[TILE * NCH];   // 43520 B -> 3 blocks/CU

    const int t = threadIdx.x;

    float4 v[LITERS];

    auto load_tile = [&](int g) {
        int ba   = g / TPB;
        int tile = g - ba * TPB;
        int s0   = tile * TILE;
        const float* inb = in + (long)ba * (NCH * GG);
        #pragma unroll
        for (int i = 0; i < LITERS; ++i) {
            int idx = t + i * THREADS;
            int c   = idx >> 5;         // channel (32 quads per channel)
            int q   = idx & 31;
            int pos = s0 + q * 4;
            if (idx < LOAD_UNITS && pos < GG)
                v[i] = *reinterpret_cast<const float4*>(&inb[(long)c * GG + pos]);
        }
    };

    auto transform_write = [&](int g) {
        int ba   = g / TPB;
        int tile = g - ba * TPB;
        int a    = ba % NA;
        int s0   = tile * TILE;
        float aw = anchors[2 * a];
        float ah = anchors[2 * a + 1];
        #pragma unroll
        for (int i = 0; i < LITERS; ++i) {
            int idx = t + i * THREADS;
            int c   = idx >> 5;
            int q   = idx & 31;
            int pos = s0 + q * 4;
            if (idx < LOAD_UNITS && pos < GG) {
                float r[4] = {v[i].x, v[i].y, v[i].z, v[i].w};
                if (c == 0) {
                    #pragma unroll
                    for (int k = 0; k < 4; ++k) {
                        int p = pos + k;
                        float gx = (float)(p - (p / GDIM) * GDIM);
                        r[k] = (fast_sigmoid(r[k]) + gx) * 8.0f;
                    }
                } else if (c == 1) {
                    #pragma unroll
                    for (int k = 0; k < 4; ++k) {
                        int p = pos + k;
                        float gy = (float)(p / GDIM);
                        r[k] = (fast_sigmoid(r[k]) + gy) * 8.0f;
                    }
                } else if (c == 2) {
                    #pragma unroll
                    for (int k = 0; k < 4; ++k) r[k] = __expf(r[k]) * aw;
                } else if (c == 3) {
                    #pragma unroll
                    for (int k = 0; k < 4; ++k) r[k] = __expf(r[k]) * ah;
                } else {
                    #pragma unroll
                    for (int k = 0; k < 4; ++k) r[k] = fast_sigmoid(r[k]);
                }
                #pragma unroll
                for (int k = 0; k < 4; ++k)
                    lds[(q * 4 + k) * NCH + c] = r[k];
            }
        }
    };

    auto store_tile = [&](int g) {
        int ba    = g / TPB;
        int tile  = g - ba * TPB;
        int s0    = tile * TILE;
        int valid = (GG - s0 < TILE) ? (GG - s0) : TILE;  // 128 or 16
        int n4    = valid * NCH / 4;                       // 2720 or 340
        float4* __restrict__ outv =
            reinterpret_cast<float4*>(out + ((long)ba * GG + s0) * NCH);
        const float4* ldsv = reinterpret_cast<const float4*>(lds);
        #pragma unroll
        for (int i = 0; i < LITERS; ++i) {
            int f4 = t + i * THREADS;
            if (f4 < n4)
                outv[f4] = ldsv[f4];   // ds_read_b128 + global_store_dwordx4
        }
    };

    int g = blockIdx.x;
    load_tile(g);                       // prologue (every block has >=2 tiles)
    for (; g < NT; g += GRID) {
        transform_write(g);             // consumes v (vmcnt wait), fills LDS
        __syncthreads();
        int gn = g + GRID;
        if (gn < NT) load_tile(gn);     // issue next-tile loads
        store_tile(g);                  // LDS -> global
        __syncthreads();                // LDS drained before next overwrite
    }
}

extern "C" void kernel_launch(void* const* d_in, const int* in_sizes, int n_in,
                              void* d_out, int out_size, void* d_ws, size_t ws_size,
                              hipStream_t stream) {
    const float* pred    = (const float*)d_in[0];
    const float* anchors = (const float*)d_in[1];
    float* out           = (float*)d_out;

    yolo_kernel<<<dim3(GRID), dim3(THREADS), 0, stream>>>(pred, anchors, out);
}